// Round 6
// baseline (117.518 us; speedup 1.0000x reference)
//
#include <hip/hip_runtime.h>
#include <hip/hip_bf16.h>

// NT-Xent loss, N=4096, D=256, fp32 in, fp32 scalar out.
// loss = mean_i [ log( sum_{j != i} exp(2*cos_ij) ) - 2*cos_{i,pair(i)} ]
//
// R6 = R1's proven staging (manual coalesced uint4 -> regs -> ds_write,
// double-buffered, 1 barrier/iter, LDSB=528) + R4/R5's proven triangle
// iterator (2112 flat col-iters, row sums in regs, col sums via LDS).
//  - zn = bf16(sqrt(2*log2e)*zhat): zn.zn^T IS the exp2 exponent
//  - 256 blocks x 512 thr (8 waves x 32 rows; ~160 regs < 256 cap: no spill)
//  - 64 blocks x 9 iters + 192 x 8 = 2112; 1 block/CU
//  - diagonal 256x256 tiles (cloc<4) computed fully by row side; col side
//    skipped there to avoid double count

#define NROWS 8192
#define NHALF 4096
#define DDIM  256
#define NSTRIP 32     // 256-row strips
#define TILE  256
#define BN    64
#define LDSB  528     // bytes per staged row (512+16)
#define MAXIT 9

typedef __bf16 bf16;
typedef __bf16 bf16x4 __attribute__((ext_vector_type(4)));
typedef __bf16 bf16x8 __attribute__((ext_vector_type(8)));
typedef float  f32x4  __attribute__((ext_vector_type(4)));

__constant__ const float kSqrtC = 1.69864359f;        // sqrt(2*log2(e))
__constant__ const float kLn2   = 0.6931471805599453f;

// ---------------- k1: normalize ----------------
__global__ void k_normalize(const float* __restrict__ z1, const float* __restrict__ z2,
                            bf16* __restrict__ zn, float* __restrict__ rowsum,
                            float* __restrict__ out) {
  const int wave = threadIdx.x >> 6, lane = threadIdx.x & 63;
  const int row = blockIdx.x * 4 + wave;
  const float* src = (row < NHALF) ? z1 + (size_t)row * DDIM
                                   : z2 + (size_t)(row - NHALF) * DDIM;
  f32x4 v = *(const f32x4*)(src + lane * 4);
  float ss = v.x * v.x + v.y * v.y + v.z * v.z + v.w * v.w;
#pragma unroll
  for (int off = 1; off < 64; off <<= 1) ss += __shfl_xor(ss, off);
  const float inv = kSqrtC / fmaxf(sqrtf(ss), 1e-8f);
  bf16x4 o;
  o.x = (bf16)(v.x * inv); o.y = (bf16)(v.y * inv);
  o.z = (bf16)(v.z * inv); o.w = (bf16)(v.w * inv);
  *(bf16x4*)(zn + (size_t)row * DDIM + lane * 4) = o;
  if (lane == 0) rowsum[row] = 0.0f;
  if (blockIdx.x == 0 && threadIdx.x == 0) out[0] = 0.0f;
}

// ---------------- k2: triangle Gram row-sums of exp2 ----------------
__global__ __launch_bounds__(512, 2) void k_gram(const bf16* __restrict__ zn,
                                                 float* __restrict__ rowsum) {
  __shared__ __align__(16) unsigned char lds[2][BN * LDSB];  // 2 x 33 KB
  __shared__ float colsum[MAXIT * BN];                       // 9 x 64
  const int tid  = threadIdx.x;
  const int wave = tid >> 6, lane = tid & 63;
  const int quad = lane >> 4, l15 = lane & 15;

  // flat iter assignment: 2112 = 64*9 + 192*8
  int t0, cnt;
  if (blockIdx.x < 64) { t0 = blockIdx.x * 9; cnt = 9; }
  else                 { t0 = 576 + ((int)blockIdx.x - 64) * 8; cnt = 8; }

  // locate strip R / col-iter-within-strip (strip R has 4*(32-R) col-iters,
  // covering cols R*256 .. 8191; cloc<4 => diagonal 256x256 tile)
  int R = 0, rem = t0;
  while (rem >= 4 * (NSTRIP - R)) { rem -= 4 * (NSTRIP - R); ++R; }
  int cloc = rem;

  for (int i = tid; i < MAXIT * BN; i += 512) colsum[i] = 0.0f;

  // A fragments: wave owns rows R*256 + wave*32 + s*16 + l15; K=256, 8 chunks
  bf16x8 a[2][8];
  auto loadA = [&](int Rv) {
#pragma unroll
    for (int s = 0; s < 2; ++s) {
      const int row = Rv * TILE + wave * 32 + s * 16 + l15;
      const bf16x8* ap = (const bf16x8*)(zn + (size_t)row * DDIM);
#pragma unroll
      for (int k = 0; k < 8; ++k) a[s][k] = ap[k * 4 + quad];  // elems k*32+quad*8
    }
  };
  loadA(R);

  float sum[2][4] = {{0.f, 0.f, 0.f, 0.f}, {0.f, 0.f, 0.f, 0.f}};
  auto flush_rows = [&]() {
#pragma unroll
    for (int s = 0; s < 2; ++s)
#pragma unroll
      for (int r = 0; r < 4; ++r) {
        float v = sum[s][r];
        v += __shfl_xor(v, 1); v += __shfl_xor(v, 2);
        v += __shfl_xor(v, 4); v += __shfl_xor(v, 8);
        if (l15 == 0)
          atomicAdd(&rowsum[R * TILE + wave * 32 + s * 16 + quad * 4 + r], v);
        sum[s][r] = 0.0f;
      }
  };

  // staging: 512 threads x 4 x 16B = 64 rows x 512B, coalesced 128B runs
  const int tr = tid >> 3, tc = tid & 7;
  uint4 g[4];
  auto prefetch = [&](int colbase) {
    const unsigned char* gp = (const unsigned char*)(zn + (size_t)(colbase + tr) * DDIM);
#pragma unroll
    for (int j = 0; j < 4; ++j) g[j] = *(const uint4*)(gp + (tc + 8 * j) * 16);
  };
  auto commit = [&](int buf) {
#pragma unroll
    for (int j = 0; j < 4; ++j)
      *(uint4*)(&lds[buf][tr * LDSB + (tc + 8 * j) * 16]) = g[j];
  };

  prefetch(R * TILE + cloc * 64);
  commit(0);

  const f32x4 zero4 = {0.f, 0.f, 0.f, 0.f};

  for (int tl = 0; tl < cnt; ++tl) {
    __syncthreads();  // buf (tl&1) staged; prior reads of other buf done
    const int cur = tl & 1;
    const bool dt = (cloc < 4);  // diagonal tile: skip col-side

    if (tl + 1 < cnt) {  // prefetch next col-iter (in flight during MFMA)
      int Rn = R, cn = cloc + 1;
      if (cn == 4 * (NSTRIP - Rn)) { cn = 0; ++Rn; }
      prefetch(Rn * TILE + cn * 64);
    }

    f32x4 acc[2][4];
#pragma unroll
    for (int k = 0; k < 8; ++k) {
      bf16x8 b[4];
#pragma unroll
      for (int cs = 0; cs < 4; ++cs)
        b[cs] = *(const bf16x8*)(&lds[cur][(cs * 16 + l15) * LDSB + k * 64 + quad * 16]);
#pragma unroll
      for (int s = 0; s < 2; ++s)
#pragma unroll
        for (int cs = 0; cs < 4; ++cs)
          acc[s][cs] = __builtin_amdgcn_mfma_f32_16x16x32_bf16(
              a[s][k], b[cs], k ? acc[s][cs] : zero4, 0, 0, 0);
    }

    if (tl + 1 < cnt) commit(cur ^ 1);

    // epilogue: MFMA output IS the exp2 exponent
#pragma unroll
    for (int cs = 0; cs < 4; ++cs) {
      float cp = 0.0f;
#pragma unroll
      for (int s = 0; s < 2; ++s)
#pragma unroll
        for (int r = 0; r < 4; ++r) {
          const float v = __builtin_amdgcn_exp2f(acc[s][cs][r]);
          sum[s][r] += v;  // row-side (C layout m89: row=quad*4+reg, col=l15)
          cp += v;
        }
      if (!dt) {  // col-side: reduce this wave's 32 rows (over quads)
        cp += __shfl_xor(cp, 16);
        cp += __shfl_xor(cp, 32);
        if (lane < 16) atomicAdd(&colsum[tl * 64 + cs * 16 + l15], cp);
      }
    }

    // advance; on strip change flush row sums & reload A
    ++cloc;
    if (cloc == 4 * (NSTRIP - R) && tl + 1 < cnt) {
      flush_rows();
      ++R; cloc = 0;
      loadA(R);
    }
  }
  flush_rows();

  __syncthreads();
  // col flush: recompute global col per local iter (diag iters hold 0)
  for (int idx = tid; idx < cnt * 64; idx += 512) {
    const int tloc = idx >> 6;
    int Rv = 0, r2 = t0 + tloc;
    while (r2 >= 4 * (NSTRIP - Rv)) { r2 -= 4 * (NSTRIP - Rv); ++Rv; }
    const int col = Rv * TILE + r2 * 64 + (idx & 63);
    atomicAdd(&rowsum[col], colsum[idx]);
  }
}

// ---------------- k3: finalize (pairs) ----------------
__device__ __forceinline__ float dot4(bf16x4 a, bf16x4 b) {
  return (float)a.x * (float)b.x + (float)a.y * (float)b.y +
         (float)a.z * (float)b.z + (float)a.w * (float)b.w;
}

__global__ void k_finalize(const bf16* __restrict__ zn, const float* __restrict__ rowsum,
                           float* __restrict__ out) {
  const int wave = threadIdx.x >> 6, lane = threadIdx.x & 63;
  const int gw = blockIdx.x * 4 + wave;  // 0..255, 16 pairs each
  float acc = 0.0f;
  for (int t = 0; t < 16; ++t) {
    const int q = gw * 16 + t, pq = q + NHALF;
    bf16x4 zq = *(const bf16x4*)(zn + (size_t)q  * DDIM + lane * 4);
    bf16x4 zp = *(const bf16x4*)(zn + (size_t)pq * DDIM + lane * 4);
    float dqq = dot4(zq, zq);  // exp2 exponent of Gram diagonal, row q
    float dpp = dot4(zp, zp);  // row pq
    float dqp = dot4(zq, zp);  // = 2*log2e*cos(q,pq); sim = dqp*ln2
#pragma unroll
    for (int off = 1; off < 64; off <<= 1) {
      dqq += __shfl_xor(dqq, off);
      dpp += __shfl_xor(dpp, off);
      dqp += __shfl_xor(dqp, off);
    }
    if (lane == 0) {
      const float lseq = __builtin_amdgcn_logf(rowsum[q]  - __builtin_amdgcn_exp2f(dqq)) * kLn2;
      const float lsep = __builtin_amdgcn_logf(rowsum[pq] - __builtin_amdgcn_exp2f(dpp)) * kLn2;
      acc += lseq + lsep - 2.0f * dqp * kLn2;
    }
  }
  __shared__ float ws4[4];
  if (lane == 0) ws4[wave] = acc;
  __syncthreads();
  if (threadIdx.x == 0)
    atomicAdd(out, (ws4[0] + ws4[1] + ws4[2] + ws4[3]) * (1.0f / (float)NROWS));
}

extern "C" void kernel_launch(void* const* d_in, const int* in_sizes, int n_in,
                              void* d_out, int out_size, void* d_ws, size_t ws_size,
                              hipStream_t stream) {
  const float* z1 = (const float*)d_in[0];
  const float* z2 = (const float*)d_in[1];
  unsigned char* ws = (unsigned char*)d_ws;

  // ws: zn bf16[8192*256] (4 MB) | rowsum f32[8192]
  bf16* zn = (bf16*)ws;
  float* rowsum = (float*)(ws + (size_t)NROWS * DDIM * sizeof(bf16));
  float* out = (float*)d_out;

  hipLaunchKernelGGL(k_normalize, dim3(NROWS / 4), dim3(256), 0, stream, z1, z2, zn, rowsum, out);
  hipLaunchKernelGGL(k_gram, dim3(256), dim3(512), 0, stream, zn, rowsum);
  hipLaunchKernelGGL(k_finalize, dim3(64), dim3(256), 0, stream, zn, rowsum, out);
}